// Round 10
// baseline (214.095 us; speedup 1.0000x reference)
//
#include <hip/hip_runtime.h>
#include <math.h>

// Problem constants
// B=2, H=128, W=256, MD=34, LD=32, NH=4, HD=8, SH=64, K=25, P=7, R=3,
// FF1=512, FF2=256

typedef __attribute__((ext_vector_type(8))) short bfrag;    // 8 bf16 = 4 VGPR
typedef __attribute__((ext_vector_type(4))) float ffrag;    // 4 f32 acc
typedef __attribute__((ext_vector_type(4))) short short4v;  // 8B

union bfi4 { int4 i; bfrag b; };

// Fast tanh-form GELU (~7 VALU ops, |err| vs erf-GELU ~3e-3)
__device__ __forceinline__ float gelu_f(float v) {
  const float z = v * (2.3022077484f + 0.1029451564f * v * v);  // log2e folded
  const float e = __builtin_amdgcn_exp2f(-z);
  return v * __builtin_amdgcn_rcpf(1.0f + e);
}

// exact RNE (cold paths: weight prep)
__device__ __forceinline__ short f2bf(float f) {
  union { float f; unsigned u; } v; v.f = f;
  unsigned r = (v.u + 0x7fffu + ((v.u >> 16) & 1u)) >> 16;
  return (short)r;
}

// round-half-up (2 VALU ops)
__device__ __forceinline__ short f2bf_fast(float f) {
  union { float f; unsigned u; } v; v.f = f;
  return (short)((v.u + 0x8000u) >> 16);
}

__device__ __forceinline__ float bf2f(short s) {
  union { float f; unsigned u; } v;
  v.u = ((unsigned)(unsigned short)s) << 16;
  return v.f;
}

// DPP cross-lane add; butterfly reduction over 16 lanes (all lanes get sum).
template <int CTRL>
__device__ __forceinline__ float dpp_add(float v) {
  union { float f; int i; } s, t;
  s.f = v;
  t.i = __builtin_amdgcn_update_dpp(0, s.i, CTRL, 0xf, 0xf, true);
  return v + t.f;
}
__device__ __forceinline__ float reduce16(float v) {
  v = dpp_add<0xB1>(v);    // quad_perm [1,0,3,2]  = xor1
  v = dpp_add<0x4E>(v);    // quad_perm [2,3,0,1]  = xor2
  v = dpp_add<0x141>(v);   // row_half_mirror      ~ xor4 after fold
  v = dpp_add<0x140>(v);   // row_mirror           ~ xor8 after fold
  return v;
}

// staged bf16 short4 store helper
__device__ __forceinline__ void st4bf(short* p, float4 v) {
  short4v s;
  s[0] = f2bf(v.x); s[1] = f2bf(v.y); s[2] = f2bf(v.z); s[3] = f2bf(v.w);
  *(short4v*)p = s;
}

// ---------------------------------------------------------------------------
// K01: weight prep.
// bid 0..127: composed conv+MLP1 weights per latitude:
//   W2[h,par,k,(n,o)] = sum_kk G[n,o,kk] * psi[kk,h,tap(par,k)]
//   with G[n,o,kk] = sum_s hw1[n,s,o]*dw[s,kk]  (h-independent, in registers)
//   stored directly in MFMA B-frag layout -> w2b (4 MB).
// bid 128..143: fw2 kt-tile transposes. 144: fw1. 145: fw3. 146: hb1e.
// ---------------------------------------------------------------------------
__global__ __launch_bounds__(256) void k01_prep(
    const float* __restrict__ psi, const float* __restrict__ dw,
    const float* __restrict__ db,
    const float* __restrict__ fw1, const float* __restrict__ fw2,
    const float* __restrict__ fw3, const float* __restrict__ hw1,
    const float* __restrict__ hb1,
    short* __restrict__ w2b, short* __restrict__ fw1s,
    short* __restrict__ fw2s, short* __restrict__ fw3s,
    float* __restrict__ hb1e) {
  __shared__ __align__(16) char sm[33280];
  const int bid = blockIdx.x;
  const int tid = threadIdx.x;

  if (bid < 128) {            // ---- w2b: composed weights per latitude
    const int h  = bid;
    const int no = tid & 127;            // n = no>>5, o = no&31
    const int ph = tid >> 7;             // pk half: 0 -> par 0, 1 -> par 1
    // hw1 column (coalesced over o)
    float hv[64];
#pragma unroll
    for (int s = 0; s < 64; ++s)
      hv[s] = hw1[(no >> 5) * 2048 + s * 32 + (no & 31)];
    // G[kk] = sum_s hv[s]*dw[s,kk]; dw addr wave-uniform -> s_load
    float G[25];
#pragma unroll
    for (int kk = 0; kk < 25; ++kk) {
      float a = 0.f;
#pragma unroll
      for (int s = 0; s < 64; ++s) a += hv[s] * dw[s * 25 + kk];
      G[kk] = a;
    }
    short* outp = w2b + h * 16384;
    const float* psih = psi + h * 49;
#pragma unroll 1
    for (int pk = ph * 64; pk < ph * 64 + 64; ++pk) {
      const int par = pk >> 6, k = pk & 63;
      const int r = k >> 3, dlt = k & 7;
      const int j = dlt - par;
      float acc = 0.f;
      if (r < 7 && j >= 0 && j < 7) {
        const int tap = r * 7 + j;
#pragma unroll
        for (int kk = 0; kk < 25; ++kk)
          acc += G[kk] * psih[kk * 6272 + tap];   // uniform -> s_load
      }
      // B-frag layout store: frag fi covers (par,kt, no-tile)
      const int kt = k >> 5, kq = (k >> 3) & 3, jj = k & 7;
      const int fi = (par * 2 + kt) * 8 + (no >> 4);
      outp[fi * 512 + (kq * 16 + (no & 15)) * 8 + jj] = f2bf(acc);
    }
    return;
  }

  if (bid < 144) {            // ---- fw2 kt-tile transpose: K rows 32, N 256
    short* S = (short*)sm;               // [32][260]
    const int kt = bid - 128;
    const float* src = fw2 + kt * 8192;
    for (int q = tid; q < 2048; q += 256) {
      const int lin = q * 4;
      const int kk = lin >> 8, nn = lin & 255;
      st4bf(S + kk * 260 + nn, *(const float4*)(src + lin));
    }
    __syncthreads();
    short* dst = fw2s + kt * 8192;
    for (int q = tid; q < 8192; q += 256) {
      const int jj = q & 7, lane = (q >> 3) & 63, nt = q >> 9;
      const int kk = (lane >> 4) * 8 + jj, nn = nt * 16 + (lane & 15);
      dst[q] = S[kk * 260 + nn];
    }
    return;
  }

  if (bid == 144) {           // ---- fw1 transpose: K 32, N 512
    short* S = (short*)sm;               // [32][516]
    for (int q = tid; q < 4096; q += 256) {
      const int lin = q * 4;
      const int kk = lin >> 9, nn = lin & 511;
      st4bf(S + kk * 516 + nn, *(const float4*)(fw1 + lin));
    }
    __syncthreads();
    for (int q = tid; q < 16384; q += 256) {
      const int jj = q & 7, lane = (q >> 3) & 63, nt = q >> 9;
      const int kk = (lane >> 4) * 8 + jj, nn = nt * 16 + (lane & 15);
      fw1s[q] = S[kk * 516 + nn];
    }
    return;
  }

  if (bid == 145) {           // ---- fw3 transpose: K 256, N 32
    short* S = (short*)sm;               // [256][36]
    for (int q = tid; q < 2048; q += 256) {
      const int lin = q * 4;
      const int kk = lin >> 5, nn = lin & 31;
      st4bf(S + kk * 36 + nn, *(const float4*)(fw3 + lin));
    }
    __syncthreads();
    for (int q = tid; q < 8192; q += 256) {
      const int jj = q & 7, lane = (q >> 3) & 63;
      const int nt = (q >> 9) & 1, kt = q >> 10;
      const int kk = kt * 32 + (lane >> 4) * 8 + jj, nn = nt * 16 + (lane & 15);
      fw3s[q] = S[kk * 36 + nn];
    }
    return;
  }

  // ---- bid 146: hb1e[n][o] = hb1[n][o] + sum_s hw1[n][s][o]*db[s] (exact)
  if (tid < 128) {
    const int n = tid >> 5, o = tid & 31;
    float acc = hb1[n * 32 + o];
#pragma unroll
    for (int s = 0; s < 64; ++s)
      acc += hw1[n * 2048 + s * 32 + o] * db[s];
    hb1e[tid] = acc;
  }
}

// ---------------------------------------------------------------------------
// K23: fused composed-conv + MLP2 + final MLP. grid (8,128,2), block 256.
// Phase A: taps -> ONE composed MFMA GEMM (K=64 taps, N=32 o) -> gelu ->
// hw2-dot -> reduce16 -> sM. No sD round-trip, no MLP1 MFMAs (pre-composed
// into w2b at prep time). Phase B unchanged (split-K halves).
// LDS 36224 B -> 4 blocks/CU.
// ---------------------------------------------------------------------------
__global__ __launch_bounds__(256, 4) void k23_fused(
    const float* __restrict__ x,    const short* __restrict__ w2b,
    const float* __restrict__ hb1e, const float* __restrict__ hw2,
    const float* __restrict__ hb2,
    const short* __restrict__ fw1s, const short* __restrict__ fw2s,
    const short* __restrict__ fw3s,
    const float* __restrict__ fb1,  const float* __restrict__ fb2,
    const float* __restrict__ fb3,  float* __restrict__ outb) {
  __shared__ __align__(16) char smem[36224];
  short* sX = (short*)smem;                 // phase A: [c 32][r 8][wp 48+pad]
  short* sM = (short*)(smem + 34048);       // x_mid tile (persists into B)

  const int tid = threadIdx.x;
  const int w0  = blockIdx.x * 32;
  const int h   = blockIdx.y;
  const int b   = blockIdx.z;

  {  // zero-fill sX (pads must be 0.0bf16, never garbage)
    int4* p = (int4*)sX;
    int4 z; z.x = z.y = z.z = z.w = 0;
    for (int e = tid; e < (32 * 388) / 8; e += 256) p[e] = z;
  }
  __syncthreads();

  // stage x tile as bf16; r-outer => wp = e>>4 (no integer division)
#pragma unroll 1
  for (int r = 0; r < 7; ++r) {
    int hr = h - 3 + r; hr = hr < 0 ? 0 : (hr > 127 ? 127 : hr);
    const float* __restrict__ xrow = x + (size_t)((b * 128 + hr) * 256) * 34;
    short* __restrict__ sxr = sX + r * 48;
    for (int e = tid; e < 39 * 16; e += 256) {
      const int c2 = e & 15;
      const int wp = e >> 4;
      const int wr = (w0 - 3 + wp) & 255;
      const float2 v = *(const float2*)&xrow[wr * 34 + c2 * 2];
      short* dp = sxr + (c2 * 2) * 388 + wp;
      dp[0]   = f2bf_fast(v.x);
      dp[388] = f2bf_fast(v.y);
    }
  }

  // sincos passthrough (independent of everything below)
  if (tid < 64) {
    const int wl = tid >> 1;
    const int sc = tid & 1;
    const int idx = ((b * 128 + h) * 256 + (w0 + wl)) * 34 + 32 + sc;
    outb[idx] = x[idx];
  }
  __syncthreads();

  const int lane = tid & 63, lm = lane & 15, lq = lane >> 4;
  const int n = tid >> 6;  // wave == head in phase A

  float hb1v[2], hw2v[2];
#pragma unroll
  for (int nt = 0; nt < 2; ++nt) {
    hb1v[nt] = hb1e[n * 32 + nt * 16 + lm];
    hw2v[nt] = hw2[n * 32 + nt * 16 + lm];
  }
  const float hb2n = hb2[n];

  // composed conv B-frags: [par][kt][o-tile] (block-uniform per h, wave head)
  bfrag cB2[2][2][2];
#pragma unroll
  for (int par = 0; par < 2; ++par)
#pragma unroll
    for (int kt = 0; kt < 2; ++kt)
#pragma unroll
      for (int nt = 0; nt < 2; ++nt)
        cB2[par][kt][nt] = *(const bfrag*)(w2b + h * 16384 +
                            ((par * 2 + kt) * 8 + (n * 2 + nt)) * 512 + lane * 8);

  const int* tpB = (const int*)sX;

  // ---- phase A main loop: conv-composed GEMM straight to h1
#pragma unroll 1
  for (int i = 0; i < 8; ++i) {
    const int c = n * 8 + i;

    // tap A-frags (shared by both parities): dword-aligned gathers
    const int base0 = c * 194 + lq * 24 + lm;
    bfi4 u0, u1;
    u0.i.x = tpB[base0];      u0.i.y = tpB[base0 + 1];
    u0.i.z = tpB[base0 + 2];  u0.i.w = tpB[base0 + 3];
    u1.i.x = tpB[base0 + 96]; u1.i.y = tpB[base0 + 97];
    u1.i.z = tpB[base0 + 98]; u1.i.w = tpB[base0 + 99];

#pragma unroll
    for (int par = 0; par < 2; ++par) {
      ffrag h1a = {0.f, 0.f, 0.f, 0.f}, h1b = {0.f, 0.f, 0.f, 0.f};
      h1a = __builtin_amdgcn_mfma_f32_16x16x32_bf16(u0.b, cB2[par][0][0], h1a, 0, 0, 0);
      h1a = __builtin_amdgcn_mfma_f32_16x16x32_bf16(u1.b, cB2[par][1][0], h1a, 0, 0, 0);
      h1b = __builtin_amdgcn_mfma_f32_16x16x32_bf16(u0.b, cB2[par][0][1], h1b, 0, 0, 0);
      h1b = __builtin_amdgcn_mfma_f32_16x16x32_bf16(u1.b, cB2[par][1][1], h1b, 0, 0, 0);

#pragma unroll
      for (int rr = 0; rr < 4; ++rr) {
        float v = gelu_f(h1a[rr] + hb1v[0]) * hw2v[0] +
                  gelu_f(h1b[rr] + hb1v[1]) * hw2v[1];
        v = reduce16(v);
        const int p = 2 * (lq * 4 + rr) + par;
        const float res = bf2f(sX[c * 388 + 144 + 3 + p]);  // x center tap
        if (lm == 0) sM[p * 34 + c] = f2bf_fast(v + hb2n + res);
      }
    }
  }
  __syncthreads();

  // ---- phase B: fused MLP 32->512(gelu)->256(gelu)->32 (+residual),
  // split-K: t1 in two 256-col halves.
  short* sT1h = (short*)smem;
  short* sT2  = (short*)(smem + 16896);
  const int wave = n;
  const int koff = lq * 8;
  const int mt3 = wave & 1;
  const int nt3 = wave >> 1;
  const int col3 = nt3 * 16 + lm;
  const int pixg = (b * 128 + h) * 256 + w0;

  bfrag aF[2];
#pragma unroll
  for (int mt = 0; mt < 2; ++mt)
    aF[mt] = *(const bfrag*)(sM + (mt * 16 + lm) * 34 + koff);
  float res3[4];
#pragma unroll
  for (int r = 0; r < 4; ++r)
    res3[r] = bf2f(sM[(mt3 * 16 + lq * 4 + r) * 34 + col3]);

  const int n0 = wave * 4;
  ffrag acc[2][4];
#pragma unroll
  for (int mt = 0; mt < 2; ++mt)
#pragma unroll
    for (int ni = 0; ni < 4; ++ni) acc[mt][ni] = ffrag{0.f, 0.f, 0.f, 0.f};
  const short* w2base = fw2s + n0 * 512 + lane * 8;

#pragma unroll 1
  for (int H = 0; H < 2; ++H) {
    // layer 1, half H: waves produce cols [H*256, H*256+256)
    bfrag b1f[4];
#pragma unroll
    for (int ni = 0; ni < 4; ++ni)
      b1f[ni] = *(const bfrag*)(fw1s + (H * 16 + wave * 4 + ni) * 512 + lane * 8);
#pragma unroll
    for (int ni = 0; ni < 4; ++ni) {
      const int ntl = wave * 4 + ni;          // within-half tile
#pragma unroll
      for (int mt = 0; mt < 2; ++mt) {
        ffrag cc = {0.f, 0.f, 0.f, 0.f};
        cc = __builtin_amdgcn_mfma_f32_16x16x32_bf16(aF[mt], b1f[ni], cc, 0, 0, 0);
        const int colg = H * 256 + ntl * 16 + lm;
        const float bias = fb1[colg];
#pragma unroll
        for (int r = 0; r < 4; ++r) {
          const int row = mt * 16 + lq * 4 + r;
          sT1h[row * 264 + ntl * 16 + lm] = f2bf_fast(gelu_f(cc[r] + bias));
        }
      }
    }
    __syncthreads();

    // layer 2 partial accumulation over this half's K=256
#pragma unroll 2
    for (int kt = 0; kt < 8; ++kt) {
      bfrag bv[4];
#pragma unroll
      for (int ni = 0; ni < 4; ++ni)
        bv[ni] = *(const bfrag*)(w2base + (H * 8 + kt) * 8192 + ni * 512);
      const bfrag a0 = *(const bfrag*)(sT1h + lm * 264 + kt * 32 + koff);
      const bfrag a1 = *(const bfrag*)(sT1h + (16 + lm) * 264 + kt * 32 + koff);
#pragma unroll
      for (int ni = 0; ni < 4; ++ni) {
        acc[0][ni] = __builtin_amdgcn_mfma_f32_16x16x32_bf16(a0, bv[ni], acc[0][ni], 0, 0, 0);
        acc[1][ni] = __builtin_amdgcn_mfma_f32_16x16x32_bf16(a1, bv[ni], acc[1][ni], 0, 0, 0);
      }
    }
    __syncthreads();   // before next half overwrites sT1h
  }

  // t2 epilogue
#pragma unroll
  for (int mt = 0; mt < 2; ++mt)
#pragma unroll
    for (int ni = 0; ni < 4; ++ni) {
      const int col = (n0 + ni) * 16 + lm;
      const float bias = fb2[col];
#pragma unroll
      for (int r = 0; r < 4; ++r) {
        const int row = mt * 16 + lq * 4 + r;
        sT2[row * 264 + col] = f2bf_fast(gelu_f(acc[mt][ni][r] + bias));
      }
    }
  __syncthreads();

  // layer 3
  ffrag c3 = {0.f, 0.f, 0.f, 0.f};
  const short* sA3 = sT2 + (mt3 * 16 + lm) * 264 + koff;
#pragma unroll
  for (int kt = 0; kt < 8; ++kt) {
    const bfrag a = *(const bfrag*)(sA3 + kt * 32);
    const bfrag bw = *(const bfrag*)(fw3s + nt3 * 512 + kt * 1024 + lane * 8);
    c3 = __builtin_amdgcn_mfma_f32_16x16x32_bf16(a, bw, c3, 0, 0, 0);
  }
  {
    const float bias = fb3[col3];
#pragma unroll
    for (int r = 0; r < 4; ++r) {
      const int row = mt3 * 16 + lq * 4 + r;
      outb[(pixg + row) * 34 + col3] = c3[r] + bias + res3[r];
    }
  }
}

// ---------------------------------------------------------------------------
extern "C" void kernel_launch(void* const* d_in, const int* in_sizes, int n_in,
                              void* d_out, int out_size, void* d_ws, size_t ws_size,
                              hipStream_t stream) {
  const float* x   = (const float*)d_in[0];
  const float* psi = (const float*)d_in[1];
  const float* dw  = (const float*)d_in[2];
  const float* db  = (const float*)d_in[3];
  const float* hw1 = (const float*)d_in[4];
  const float* hb1 = (const float*)d_in[5];
  const float* hw2 = (const float*)d_in[6];
  const float* hb2 = (const float*)d_in[7];
  const float* fw1 = (const float*)d_in[8];
  const float* fb1 = (const float*)d_in[9];
  const float* fw2 = (const float*)d_in[10];
  const float* fb2 = (const float*)d_in[11];
  const float* fw3 = (const float*)d_in[12];
  const float* fb3 = (const float*)d_in[13];
  float* outb = (float*)d_out;

  // workspace: w2b 4 MB + swizzled final-MLP weights (~0.31 MB)
  short* w2b  = (short*)d_ws;        // 128*16384 = 2097152 shorts
  short* fw1s = w2b + 2097152;       // 16384
  short* fw2s = fw1s + 16384;        // 131072
  short* fw3s = fw2s + 131072;       // 8192
  float* hb1e = (float*)(fw3s + 8192);  // 128 floats

  hipLaunchKernelGGL(k01_prep, dim3(147), dim3(256), 0, stream,
                     psi, dw, db, fw1, fw2, fw3, hw1, hb1,
                     w2b, fw1s, fw2s, fw3s, hb1e);
  hipLaunchKernelGGL(k23_fused, dim3(8, 128, 2), dim3(256), 0, stream,
                     x, w2b, hb1e, hw2, hb2,
                     fw1s, fw2s, fw3s, fb1, fb2, fb3, outb);
}

// Round 11
// 177.670 us; speedup vs baseline: 1.2050x; 1.2050x over previous
//
#include <hip/hip_runtime.h>
#include <math.h>

// Problem constants
// B=2, H=128, W=256, MD=34, LD=32, NH=4, HD=8, SH=64, K=25, P=7, R=3,
// FF1=512, FF2=256

typedef __attribute__((ext_vector_type(8))) short bfrag;    // 8 bf16 = 4 VGPR
typedef __attribute__((ext_vector_type(4))) float ffrag;    // 4 f32 acc
typedef __attribute__((ext_vector_type(4))) short short4v;  // 8B

union bfi4 { int4 i; bfrag b; };

// Fast tanh-form GELU (~7 VALU ops, |err| vs erf-GELU ~3e-3)
__device__ __forceinline__ float gelu_f(float v) {
  const float z = v * (2.3022077484f + 0.1029451564f * v * v);  // log2e folded
  const float e = __builtin_amdgcn_exp2f(-z);
  return v * __builtin_amdgcn_rcpf(1.0f + e);
}

// exact RNE (cold paths: weight prep)
__device__ __forceinline__ short f2bf(float f) {
  union { float f; unsigned u; } v; v.f = f;
  unsigned r = (v.u + 0x7fffu + ((v.u >> 16) & 1u)) >> 16;
  return (short)r;
}

// round-half-up (2 VALU ops)
__device__ __forceinline__ short f2bf_fast(float f) {
  union { float f; unsigned u; } v; v.f = f;
  return (short)((v.u + 0x8000u) >> 16);
}

__device__ __forceinline__ float bf2f(short s) {
  union { float f; unsigned u; } v;
  v.u = ((unsigned)(unsigned short)s) << 16;
  return v.f;
}

// RNE pack of two f32 into one dword of bf16 pairs (cold path)
__device__ __forceinline__ unsigned pk2rne(float a, float b) {
  return ((unsigned)(unsigned short)f2bf(b) << 16) | (unsigned short)f2bf(a);
}

// DPP cross-lane add; butterfly reduction over 16 lanes (all lanes get sum).
template <int CTRL>
__device__ __forceinline__ float dpp_add(float v) {
  union { float f; int i; } s, t;
  s.f = v;
  t.i = __builtin_amdgcn_update_dpp(0, s.i, CTRL, 0xf, 0xf, true);
  return v + t.f;
}
__device__ __forceinline__ float reduce16(float v) {
  v = dpp_add<0xB1>(v);    // quad_perm [1,0,3,2]  = xor1
  v = dpp_add<0x4E>(v);    // quad_perm [2,3,0,1]  = xor2
  v = dpp_add<0x141>(v);   // row_half_mirror      ~ xor4 after fold
  v = dpp_add<0x140>(v);   // row_mirror           ~ xor8 after fold
  return v;
}

// staged bf16 short4 store helper
__device__ __forceinline__ void st4bf(short* p, float4 v) {
  short4v s;
  s[0] = f2bf(v.x); s[1] = f2bf(v.y); s[2] = f2bf(v.z); s[3] = f2bf(v.w);
  *(short4v*)p = s;
}

// ---------------------------------------------------------------------------
// K01: weight prep.
// bid 0..127: composed conv+MLP1 weights per latitude (REWORKED vs R9):
//   W2[h,par,k,(n,o)] = sum_kk G[no,kk] * psi[kk,h,tap(par,k)]
//   G computed COOPERATIVELY via LDS (no per-thread hv[64] spill);
//   psi staged transposed in LDS (contiguous 25-float rows -> ds_read_b128);
//   emission packs 8 taps -> one coalesced 16B store.
// bid 128..143: fw2 kt-tile transposes. 144: fw1. 145: fw3. 146: hb1e.
// ---------------------------------------------------------------------------
__global__ __launch_bounds__(256) void k01_prep(
    const float* __restrict__ psi, const float* __restrict__ dw,
    const float* __restrict__ db,
    const float* __restrict__ fw1, const float* __restrict__ fw2,
    const float* __restrict__ fw3, const float* __restrict__ hw1,
    const float* __restrict__ hb1,
    short* __restrict__ w2b, short* __restrict__ fw1s,
    short* __restrict__ fw2s, short* __restrict__ fw3s,
    float* __restrict__ hb1e) {
  __shared__ __align__(16) char sm[57456];
  const int bid = blockIdx.x;
  const int tid = threadIdx.x;

  if (bid < 128) {            // ---- w2b: composed weights per latitude
    float* psiT = (float*)sm;              // [tap 49][kk pad 28]   5488 B
    float* GL   = (float*)(sm + 5488);     // [kk 25][no 128]      12800 B
    float* hwL  = (float*)(sm + 18288);    // [s 64][no 128]       32768 B
    float* dwL  = (float*)(sm + 51056);    // [s 64][kk 25]         6400 B
    const int h = bid;

    // stage psi transposed (coalesced read, LDS scatter)
    for (int e = tid; e < 1225; e += 256) {
      const int kk = e / 49, tap = e - kk * 49;
      psiT[tap * 28 + kk] = psi[kk * 6272 + h * 49 + tap];
    }
    // stage hw1 -> hwL[s][n*32+o]
    for (int l = tid; l < 8192; l += 256) {
      const int n = l >> 11, s = (l >> 5) & 63, o = l & 31;
      hwL[s * 128 + n * 32 + o] = hw1[l];
    }
    for (int l = tid; l < 1600; l += 256) dwL[l] = dw[l];
    __syncthreads();

    const int no  = tid & 127;   // n = no>>5, o = no&31
    const int ph  = tid >> 7;    // = par (uniform per wave)
    // G cooperative: ph0 -> kk 0..12, ph1 -> kk 13..24
    const int k0 = ph ? 13 : 0, k1 = ph ? 25 : 13;
#pragma unroll 1
    for (int kk = k0; kk < k1; ++kk) {
      float a = 0.f;
#pragma unroll
      for (int s = 0; s < 64; ++s) a += hwL[s * 128 + no] * dwL[s * 25 + kk];
      GL[kk * 128 + no] = a;
    }
    __syncthreads();
    float Greg[25];
#pragma unroll
    for (int kk = 0; kk < 25; ++kk) Greg[kk] = GL[kk * 128 + no];

    short* outp = w2b + h * 16384;
    const int par = ph;
#pragma unroll 1
    for (int kt = 0; kt < 2; ++kt) {
#pragma unroll 1
      for (int kq = 0; kq < 4; ++kq) {
        const int r = kt * 4 + kq;
        unsigned pack[4] = {0u, 0u, 0u, 0u};
        if (r < 7) {
          float accs[8];
#pragma unroll
          for (int jj = 0; jj < 8; ++jj) {
            const int j = jj - par;
            float a = 0.f;
            if (j >= 0 && j < 7) {
              const float* pt = psiT + (r * 7 + j) * 28;   // 16B-aligned row
#pragma unroll
              for (int kk = 0; kk < 25; ++kk) a += Greg[kk] * pt[kk];
            }
            accs[jj] = a;
          }
#pragma unroll
          for (int q = 0; q < 4; ++q)
            pack[q] = pk2rne(accs[2 * q], accs[2 * q + 1]);
        }
        // B-frag store: frag fi=(par*2+kt)*8+(no>>4), lane=kq*16+(no&15)
        const int fi = (par * 2 + kt) * 8 + (no >> 4);
        *(int4*)(outp + fi * 512 + (kq * 16 + (no & 15)) * 8) = *(int4*)pack;
      }
    }
    return;
  }

  if (bid < 144) {            // ---- fw2 kt-tile transpose: K rows 32, N 256
    short* S = (short*)sm;               // [32][260]
    const int kt = bid - 128;
    const float* src = fw2 + kt * 8192;
    for (int q = tid; q < 2048; q += 256) {
      const int lin = q * 4;
      const int kk = lin >> 8, nn = lin & 255;
      st4bf(S + kk * 260 + nn, *(const float4*)(src + lin));
    }
    __syncthreads();
    short* dst = fw2s + kt * 8192;
    for (int q = tid; q < 8192; q += 256) {
      const int jj = q & 7, lane = (q >> 3) & 63, nt = q >> 9;
      const int kk = (lane >> 4) * 8 + jj, nn = nt * 16 + (lane & 15);
      dst[q] = S[kk * 260 + nn];
    }
    return;
  }

  if (bid == 144) {           // ---- fw1 transpose: K 32, N 512
    short* S = (short*)sm;               // [32][516]
    for (int q = tid; q < 4096; q += 256) {
      const int lin = q * 4;
      const int kk = lin >> 9, nn = lin & 511;
      st4bf(S + kk * 516 + nn, *(const float4*)(fw1 + lin));
    }
    __syncthreads();
    for (int q = tid; q < 16384; q += 256) {
      const int jj = q & 7, lane = (q >> 3) & 63, nt = q >> 9;
      const int kk = (lane >> 4) * 8 + jj, nn = nt * 16 + (lane & 15);
      fw1s[q] = S[kk * 516 + nn];
    }
    return;
  }

  if (bid == 145) {           // ---- fw3 transpose: K 256, N 32
    short* S = (short*)sm;               // [256][36]
    for (int q = tid; q < 2048; q += 256) {
      const int lin = q * 4;
      const int kk = lin >> 5, nn = lin & 31;
      st4bf(S + kk * 36 + nn, *(const float4*)(fw3 + lin));
    }
    __syncthreads();
    for (int q = tid; q < 8192; q += 256) {
      const int jj = q & 7, lane = (q >> 3) & 63;
      const int nt = (q >> 9) & 1, kt = q >> 10;
      const int kk = kt * 32 + (lane >> 4) * 8 + jj, nn = nt * 16 + (lane & 15);
      fw3s[q] = S[kk * 36 + nn];
    }
    return;
  }

  // ---- bid 146: hb1e[n][o] = hb1[n][o] + sum_s hw1[n][s][o]*db[s] (exact)
  if (tid < 128) {
    const int n = tid >> 5, o = tid & 31;
    float acc = hb1[n * 32 + o];
#pragma unroll
    for (int s = 0; s < 64; ++s)
      acc += hw1[n * 2048 + s * 32 + o] * db[s];
    hb1e[tid] = acc;
  }
}

// ---------------------------------------------------------------------------
// K23: fused composed-conv + MLP2 + final MLP. grid (8,128,2), block 256.
// (byte-identical to R9 -- isolates the k01 fix)
// ---------------------------------------------------------------------------
__global__ __launch_bounds__(256, 4) void k23_fused(
    const float* __restrict__ x,    const short* __restrict__ w2b,
    const float* __restrict__ hb1e, const float* __restrict__ hw2,
    const float* __restrict__ hb2,
    const short* __restrict__ fw1s, const short* __restrict__ fw2s,
    const short* __restrict__ fw3s,
    const float* __restrict__ fb1,  const float* __restrict__ fb2,
    const float* __restrict__ fb3,  float* __restrict__ outb) {
  __shared__ __align__(16) char smem[36224];
  short* sX = (short*)smem;                 // phase A: [c 32][r 8][wp 48+pad]
  short* sM = (short*)(smem + 34048);       // x_mid tile (persists into B)

  const int tid = threadIdx.x;
  const int w0  = blockIdx.x * 32;
  const int h   = blockIdx.y;
  const int b   = blockIdx.z;

  {  // zero-fill sX (pads must be 0.0bf16, never garbage)
    int4* p = (int4*)sX;
    int4 z; z.x = z.y = z.z = z.w = 0;
    for (int e = tid; e < (32 * 388) / 8; e += 256) p[e] = z;
  }
  __syncthreads();

  // stage x tile as bf16; r-outer => wp = e>>4 (no integer division)
#pragma unroll 1
  for (int r = 0; r < 7; ++r) {
    int hr = h - 3 + r; hr = hr < 0 ? 0 : (hr > 127 ? 127 : hr);
    const float* __restrict__ xrow = x + (size_t)((b * 128 + hr) * 256) * 34;
    short* __restrict__ sxr = sX + r * 48;
    for (int e = tid; e < 39 * 16; e += 256) {
      const int c2 = e & 15;
      const int wp = e >> 4;
      const int wr = (w0 - 3 + wp) & 255;
      const float2 v = *(const float2*)&xrow[wr * 34 + c2 * 2];
      short* dp = sxr + (c2 * 2) * 388 + wp;
      dp[0]   = f2bf_fast(v.x);
      dp[388] = f2bf_fast(v.y);
    }
  }

  // sincos passthrough (independent of everything below)
  if (tid < 64) {
    const int wl = tid >> 1;
    const int sc = tid & 1;
    const int idx = ((b * 128 + h) * 256 + (w0 + wl)) * 34 + 32 + sc;
    outb[idx] = x[idx];
  }
  __syncthreads();

  const int lane = tid & 63, lm = lane & 15, lq = lane >> 4;
  const int n = tid >> 6;  // wave == head in phase A

  float hb1v[2], hw2v[2];
#pragma unroll
  for (int nt = 0; nt < 2; ++nt) {
    hb1v[nt] = hb1e[n * 32 + nt * 16 + lm];
    hw2v[nt] = hw2[n * 32 + nt * 16 + lm];
  }
  const float hb2n = hb2[n];

  // composed conv B-frags: [par][kt][o-tile] (block-uniform per h, wave head)
  bfrag cB2[2][2][2];
#pragma unroll
  for (int par = 0; par < 2; ++par)
#pragma unroll
    for (int kt = 0; kt < 2; ++kt)
#pragma unroll
      for (int nt = 0; nt < 2; ++nt)
        cB2[par][kt][nt] = *(const bfrag*)(w2b + h * 16384 +
                            ((par * 2 + kt) * 8 + (n * 2 + nt)) * 512 + lane * 8);

  const int* tpB = (const int*)sX;

  // ---- phase A main loop: conv-composed GEMM straight to h1
#pragma unroll 1
  for (int i = 0; i < 8; ++i) {
    const int c = n * 8 + i;

    // tap A-frags (shared by both parities): dword-aligned gathers
    const int base0 = c * 194 + lq * 24 + lm;
    bfi4 u0, u1;
    u0.i.x = tpB[base0];      u0.i.y = tpB[base0 + 1];
    u0.i.z = tpB[base0 + 2];  u0.i.w = tpB[base0 + 3];
    u1.i.x = tpB[base0 + 96]; u1.i.y = tpB[base0 + 97];
    u1.i.z = tpB[base0 + 98]; u1.i.w = tpB[base0 + 99];

#pragma unroll
    for (int par = 0; par < 2; ++par) {
      ffrag h1a = {0.f, 0.f, 0.f, 0.f}, h1b = {0.f, 0.f, 0.f, 0.f};
      h1a = __builtin_amdgcn_mfma_f32_16x16x32_bf16(u0.b, cB2[par][0][0], h1a, 0, 0, 0);
      h1a = __builtin_amdgcn_mfma_f32_16x16x32_bf16(u1.b, cB2[par][1][0], h1a, 0, 0, 0);
      h1b = __builtin_amdgcn_mfma_f32_16x16x32_bf16(u0.b, cB2[par][0][1], h1b, 0, 0, 0);
      h1b = __builtin_amdgcn_mfma_f32_16x16x32_bf16(u1.b, cB2[par][1][1], h1b, 0, 0, 0);

#pragma unroll
      for (int rr = 0; rr < 4; ++rr) {
        float v = gelu_f(h1a[rr] + hb1v[0]) * hw2v[0] +
                  gelu_f(h1b[rr] + hb1v[1]) * hw2v[1];
        v = reduce16(v);
        const int p = 2 * (lq * 4 + rr) + par;
        const float res = bf2f(sX[c * 388 + 144 + 3 + p]);  // x center tap
        if (lm == 0) sM[p * 34 + c] = f2bf_fast(v + hb2n + res);
      }
    }
  }
  __syncthreads();

  // ---- phase B: fused MLP 32->512(gelu)->256(gelu)->32 (+residual),
  // split-K: t1 in two 256-col halves.
  short* sT1h = (short*)smem;
  short* sT2  = (short*)(smem + 16896);
  const int wave = n;
  const int koff = lq * 8;
  const int mt3 = wave & 1;
  const int nt3 = wave >> 1;
  const int col3 = nt3 * 16 + lm;
  const int pixg = (b * 128 + h) * 256 + w0;

  bfrag aF[2];
#pragma unroll
  for (int mt = 0; mt < 2; ++mt)
    aF[mt] = *(const bfrag*)(sM + (mt * 16 + lm) * 34 + koff);
  float res3[4];
#pragma unroll
  for (int r = 0; r < 4; ++r)
    res3[r] = bf2f(sM[(mt3 * 16 + lq * 4 + r) * 34 + col3]);

  const int n0 = wave * 4;
  ffrag acc[2][4];
#pragma unroll
  for (int mt = 0; mt < 2; ++mt)
#pragma unroll
    for (int ni = 0; ni < 4; ++ni) acc[mt][ni] = ffrag{0.f, 0.f, 0.f, 0.f};
  const short* w2base = fw2s + n0 * 512 + lane * 8;

#pragma unroll 1
  for (int H = 0; H < 2; ++H) {
    // layer 1, half H: waves produce cols [H*256, H*256+256)
    bfrag b1f[4];
#pragma unroll
    for (int ni = 0; ni < 4; ++ni)
      b1f[ni] = *(const bfrag*)(fw1s + (H * 16 + wave * 4 + ni) * 512 + lane * 8);
#pragma unroll
    for (int ni = 0; ni < 4; ++ni) {
      const int ntl = wave * 4 + ni;          // within-half tile
#pragma unroll
      for (int mt = 0; mt < 2; ++mt) {
        ffrag cc = {0.f, 0.f, 0.f, 0.f};
        cc = __builtin_amdgcn_mfma_f32_16x16x32_bf16(aF[mt], b1f[ni], cc, 0, 0, 0);
        const int colg = H * 256 + ntl * 16 + lm;
        const float bias = fb1[colg];
#pragma unroll
        for (int r = 0; r < 4; ++r) {
          const int row = mt * 16 + lq * 4 + r;
          sT1h[row * 264 + ntl * 16 + lm] = f2bf_fast(gelu_f(cc[r] + bias));
        }
      }
    }
    __syncthreads();

    // layer 2 partial accumulation over this half's K=256
#pragma unroll 2
    for (int kt = 0; kt < 8; ++kt) {
      bfrag bv[4];
#pragma unroll
      for (int ni = 0; ni < 4; ++ni)
        bv[ni] = *(const bfrag*)(w2base + (H * 8 + kt) * 8192 + ni * 512);
      const bfrag a0 = *(const bfrag*)(sT1h + lm * 264 + kt * 32 + koff);
      const bfrag a1 = *(const bfrag*)(sT1h + (16 + lm) * 264 + kt * 32 + koff);
#pragma unroll
      for (int ni = 0; ni < 4; ++ni) {
        acc[0][ni] = __builtin_amdgcn_mfma_f32_16x16x32_bf16(a0, bv[ni], acc[0][ni], 0, 0, 0);
        acc[1][ni] = __builtin_amdgcn_mfma_f32_16x16x32_bf16(a1, bv[ni], acc[1][ni], 0, 0, 0);
      }
    }
    __syncthreads();   // before next half overwrites sT1h
  }

  // t2 epilogue
#pragma unroll
  for (int mt = 0; mt < 2; ++mt)
#pragma unroll
    for (int ni = 0; ni < 4; ++ni) {
      const int col = (n0 + ni) * 16 + lm;
      const float bias = fb2[col];
#pragma unroll
      for (int r = 0; r < 4; ++r) {
        const int row = mt * 16 + lq * 4 + r;
        sT2[row * 264 + col] = f2bf_fast(gelu_f(acc[mt][ni][r] + bias));
      }
    }
  __syncthreads();

  // layer 3
  ffrag c3 = {0.f, 0.f, 0.f, 0.f};
  const short* sA3 = sT2 + (mt3 * 16 + lm) * 264 + koff;
#pragma unroll
  for (int kt = 0; kt < 8; ++kt) {
    const bfrag a = *(const bfrag*)(sA3 + kt * 32);
    const bfrag bw = *(const bfrag*)(fw3s + nt3 * 512 + kt * 1024 + lane * 8);
    c3 = __builtin_amdgcn_mfma_f32_16x16x32_bf16(a, bw, c3, 0, 0, 0);
  }
  {
    const float bias = fb3[col3];
#pragma unroll
    for (int r = 0; r < 4; ++r) {
      const int row = mt3 * 16 + lq * 4 + r;
      outb[(pixg + row) * 34 + col3] = c3[r] + bias + res3[r];
    }
  }
}

// ---------------------------------------------------------------------------
extern "C" void kernel_launch(void* const* d_in, const int* in_sizes, int n_in,
                              void* d_out, int out_size, void* d_ws, size_t ws_size,
                              hipStream_t stream) {
  const float* x   = (const float*)d_in[0];
  const float* psi = (const float*)d_in[1];
  const float* dw  = (const float*)d_in[2];
  const float* db  = (const float*)d_in[3];
  const float* hw1 = (const float*)d_in[4];
  const float* hb1 = (const float*)d_in[5];
  const float* hw2 = (const float*)d_in[6];
  const float* hb2 = (const float*)d_in[7];
  const float* fw1 = (const float*)d_in[8];
  const float* fb1 = (const float*)d_in[9];
  const float* fw2 = (const float*)d_in[10];
  const float* fb2 = (const float*)d_in[11];
  const float* fw3 = (const float*)d_in[12];
  const float* fb3 = (const float*)d_in[13];
  float* outb = (float*)d_out;

  // workspace: w2b 4 MB + swizzled final-MLP weights (~0.31 MB)
  short* w2b  = (short*)d_ws;        // 128*16384 = 2097152 shorts
  short* fw1s = w2b + 2097152;       // 16384
  short* fw2s = fw1s + 16384;        // 131072
  short* fw3s = fw2s + 131072;       // 8192
  float* hb1e = (float*)(fw3s + 8192);  // 128 floats

  hipLaunchKernelGGL(k01_prep, dim3(147), dim3(256), 0, stream,
                     psi, dw, db, fw1, fw2, fw3, hw1, hb1,
                     w2b, fw1s, fw2s, fw3s, hb1e);
  hipLaunchKernelGGL(k23_fused, dim3(8, 128, 2), dim3(256), 0, stream,
                     x, w2b, hb1e, hw2, hb2,
                     fw1s, fw2s, fw3s, fb1, fb2, fb3, outb);
}